// Round 12
// baseline (101.831 us; speedup 1.0000x reference)
//
#include <hip/hip_runtime.h>
#include <hip/hip_bf16.h>

// CapsuleLayer dynamic routing, MI355X. fp32 in/out.
// C=10, B=128, N=1152, IN=8, OUT=16, 3 routing iters.
//
// v10 (round 12): r10 monolith with THREADS=768 (12 waves). ONE change.
//   r11's two-kernel split REGRESSED (~50 us vs r10's 41.8): the 94 MB
//   priors round-trip + kernel-boundary serialization cost more than the
//   330 MB of L2 W-traffic it saved. Reverted.
//   r10 counters: LDS 75.3 KB -> 2 blocks/CU (LDS-capped, T-independent);
//   at T=512 that's 16 waves/CU (50%) and 640/512 = 2.5 dispatch rounds
//   (time-avg occupancy 28.6%). T=768 keeps 2 blocks/CU but gives
//   24 waves/CU (75% cap) and 1.25 rounds. Per-thread passes 9 -> 6.
//
// Structure (r10-proven): G=2, one block per (c, b-pair), 640 blocks.
//   P in LDS as bf16x2 (register-array P is trapped between load-hoisting
//   into AGPRs [r5-r8: 1.4 waves/SIMD] and scratch demotion [r9: 46 MB]).
//   Thread-private P slots (no barrier; lgkmcnt orders same-thread RAW).
//   Lane l: o-quad q=l&3 (owns o=q*4..+3), row-sub rsub=l>>2; wave w covers
//   rows [w*96,(w+1)*96) in 6 passes of 16. W float4 load = 16 rows x 64 B
//   fully-consumed lines (coalescing minimum). fp32 accumulation everywhere;
//   only P storage is bf16 (absmax 0.0078 vs threshold 0.0172, 2.2x margin).
//   Logit state eliminated: logit = dot(accum-out, P) recomputed per iter.
//   Unnormalized softmax (|logit| <~ 30, fp32-safe).

constexpr int C = 10, B = 128, N = 1152, IN = 8, OUT = 16;
constexpr int THREADS = 768;
constexpr int NW = THREADS / 64;          // 12 waves
constexpr int G = 2;                      // batches per block
constexpr int PASSES = N / (NW * 16);     // 6

__device__ __forceinline__ unsigned packbf(float a, float b) {
    __hip_bfloat162 h = __float22bfloat162_rn(float2{a, b});  // RNE
    return *(unsigned*)&h;
}
__device__ __forceinline__ float bflo(unsigned u) { return __uint_as_float(u << 16); }
__device__ __forceinline__ float bfhi(unsigned u) { return __uint_as_float(u & 0xffff0000u); }

__global__ __launch_bounds__(THREADS)
void caps_route(const float* __restrict__ Xf, const float* __restrict__ Wf,
                float* __restrict__ Of) {
    // P packed: .x = bf16x2(P0,P1), .y = bf16x2(P2,P3); thread-private slots
    __shared__ uint2 ldsP[G * PASSES * THREADS];       // 73,728 B
    __shared__ float lds_s[G][NW][OUT];                // per-wave weighted sums
    __shared__ float lds_sum[G][NW];                   // per-wave softmax denoms
    __shared__ float lds_out[G][OUT];                  // squashed outputs

    const int t = threadIdx.x;
    const int l = t & 63;
    const int wid = t >> 6;
    const int q = l & 3;        // o-quad: owns o = q*4 .. q*4+3
    const int rsub = l >> 2;    // row-sub within a pass (0..15)
    const int blk = blockIdx.x;
    const int c = blk >> 6;     // 64 consecutive blocks share c -> W[c] in L2
    const int b0 = (blk & 63) * G;

    // ---- priors: P[n][o] = sum_i x[b,n,i] * W[c,n,i,o] (fp32 acc, bf16 store)
    #pragma unroll
    for (int p = 0; p < PASSES; ++p) {
        const int n = wid * (16 * PASSES) + p * 16 + rsub;
        const float4* wr = (const float4*)(Wf + (size_t)(c * N + n) * (IN * OUT));
        float4 wv[IN];
        #pragma unroll
        for (int i = 0; i < IN; ++i) wv[i] = wr[i * 4 + q];   // 16 full lines/instr
        #pragma unroll
        for (int g = 0; g < G; ++g) {
            const float4* xr = (const float4*)(Xf + (size_t)((b0 + g) * N + n) * IN);
            const float4 xa = xr[0], xc = xr[1];
            const float xs[8] = { xa.x, xa.y, xa.z, xa.w, xc.x, xc.y, xc.z, xc.w };
            float a0 = 0.f, a1 = 0.f, a2 = 0.f, a3 = 0.f;
            #pragma unroll
            for (int i = 0; i < IN; ++i) {
                a0 = fmaf(xs[i], wv[i].x, a0);
                a1 = fmaf(xs[i], wv[i].y, a1);
                a2 = fmaf(xs[i], wv[i].z, a2);
                a3 = fmaf(xs[i], wv[i].w, a3);
            }
            ldsP[(g * PASSES + p) * THREADS + t] =
                uint2{packbf(a0, a1), packbf(a2, a3)};
        }
    }

    // accumulated output quad-slice (fp32); logit[p] == dot(oa_full16, P[p])
    float oa[G][4];
    #pragma unroll
    for (int g = 0; g < G; ++g)
        #pragma unroll
        for (int k = 0; k < 4; ++k) oa[g][k] = 0.f;

    // ---- dynamic routing ----
    for (int it = 0; it < 3; ++it) {
        float s4[G][4];
        float ssum[G];
        if (it == 0) {
            // logits all 0 -> e = 1: plain sums
            #pragma unroll
            for (int g = 0; g < G; ++g) {
                ssum[g] = (float)PASSES;
                float a0 = 0.f, a1 = 0.f, a2 = 0.f, a3 = 0.f;
                #pragma unroll
                for (int p = 0; p < PASSES; ++p) {
                    const uint2 u = ldsP[(g * PASSES + p) * THREADS + t];
                    a0 += bflo(u.x); a1 += bfhi(u.x);
                    a2 += bflo(u.y); a3 += bfhi(u.y);
                }
                s4[g][0] = a0; s4[g][1] = a1; s4[g][2] = a2; s4[g][3] = a3;
            }
        } else {
            #pragma unroll
            for (int g = 0; g < G; ++g) {
                ssum[g] = 0.f;
                #pragma unroll
                for (int k = 0; k < 4; ++k) s4[g][k] = 0.f;
                #pragma unroll
                for (int p = 0; p < PASSES; ++p) {
                    const uint2 u = ldsP[(g * PASSES + p) * THREADS + t];
                    const float p0 = bflo(u.x), p1 = bfhi(u.x);
                    const float p2 = bflo(u.y), p3 = bfhi(u.y);
                    // logit[p] = dot(out_accum, P[p]) via quad butterfly
                    float d = oa[g][0] * p0;
                    d = fmaf(oa[g][1], p1, d);
                    d = fmaf(oa[g][2], p2, d);
                    d = fmaf(oa[g][3], p3, d);
                    d += __shfl_xor(d, 1, 64);
                    d += __shfl_xor(d, 2, 64);
                    const float e = __expf(d);      // replicated across quad
                    ssum[g] += e;
                    s4[g][0] = fmaf(e, p0, s4[g][0]);
                    s4[g][1] = fmaf(e, p1, s4[g][1]);
                    s4[g][2] = fmaf(e, p2, s4[g][2]);
                    s4[g][3] = fmaf(e, p3, s4[g][3]);
                }
            }
        }
        // reduce across the 16 row-subs of the wave (masks 4..32; quad bits
        // 0,1 carry replicas (ssum) / distinct o (s4) -> not summed)
        #pragma unroll
        for (int m = 4; m < 64; m <<= 1) {
            #pragma unroll
            for (int g = 0; g < G; ++g) {
                ssum[g] += __shfl_xor(ssum[g], m, 64);
                #pragma unroll
                for (int k = 0; k < 4; ++k) s4[g][k] += __shfl_xor(s4[g][k], m, 64);
            }
        }
        if (l < 4) {  // lane l == quad q: owns o = l*4..l*4+3
            #pragma unroll
            for (int g = 0; g < G; ++g)
                #pragma unroll
                for (int k = 0; k < 4; ++k) lds_s[g][wid][l * 4 + k] = s4[g][k];
        }
        if (l == 0) {
            #pragma unroll
            for (int g = 0; g < G; ++g) lds_sum[g][wid] = ssum[g];
        }
        __syncthreads();   // A

        // cross-wave combine + squash on t<32 (16-lane group per g)
        if (t < 32) {
            const int g = t >> 4, o = t & 15;
            float so = 0.f, S = 0.f;
            #pragma unroll
            for (int w = 0; w < NW; ++w) { so += lds_s[g][w][o]; S += lds_sum[g][w]; }
            so /= S;                          // s_o = softmax-weighted prior sum
            float r = so * so;                // ||s||^2 via 16-lane butterfly
            r += __shfl_xor(r, 1, 64);
            r += __shfl_xor(r, 2, 64);
            r += __shfl_xor(r, 4, 64);
            r += __shfl_xor(r, 8, 64);
            const float ov = so * (r / ((1.f + r) * sqrtf(r + 1e-8f)));
            if (it == 2) Of[((size_t)c * B + b0 + g) * OUT + o] = ov;
            else         lds_out[g][o] = ov;
        }

        if (it < 2) {
            __syncthreads();   // B
            #pragma unroll
            for (int g = 0; g < G; ++g)
                #pragma unroll
                for (int k = 0; k < 4; ++k) oa[g][k] += lds_out[g][q * 4 + k];
        }
    }
}

extern "C" void kernel_launch(void* const* d_in, const int* in_sizes, int n_in,
                              void* d_out, int out_size, void* d_ws, size_t ws_size,
                              hipStream_t stream) {
    const float* X = (const float*)d_in[0];   // [B,N,IN] fp32
    const float* W = (const float*)d_in[1];   // [C,N,IN,OUT] fp32
    float* O = (float*)d_out;                 // [C,B,OUT] fp32
    hipLaunchKernelGGL(caps_route, dim3(C * (B / G)), dim3(THREADS), 0, stream, X, W, O);
}

// Round 13
// 97.476 us; speedup vs baseline: 1.0447x; 1.0447x over previous
//
#include <hip/hip_runtime.h>
#include <hip/hip_bf16.h>

// CapsuleLayer dynamic routing, MI355X. fp32 in/out.
// C=10, B=128, N=1152, IN=8, OUT=16, 3 routing iters.
//
// v11 (round 13): G=1, T=512, LDS-P -> 4 blocks/CU, 32 waves/CU.
//   r12 (T=768) regressed 49 us: at 2 blocks/CU the time-avg occupancy is
//   tail-dominated ((16+4)/2 ~ 9 waves/CU for any T) — block size moves
//   neither packing granularity nor instantaneous residency. G=1 does:
//   LDS 37.5 KB -> 4 blocks/CU (150 KB), 32 waves/CU cap, and the 1280-block
//   grid tails as 1024+256 with the remainder spread 1/CU on EVERY CU (no
//   idle CUs). Deliberate trade: W L2 traffic doubles to 755 MB (~22 us L2 /
//   ~19 us TA floor) in exchange for ~3x the latency-hiding residency.
//   r10's 41.8 us is far above either floor -> betting residency binds.
//   Requires VGPR <= 64; r10 needed 56 with twice this state.
//   iter-0 fused into build: its e=1 weighted sums accumulate in fp32 while
//   priors are produced (deletes iter-0's LDS pass, slightly better accuracy).
//
// Structure: one block per (c,b), 1280 blocks, 512 thr (8 waves).
//   P in LDS as bf16x2, thread-private slots (no barrier: lgkmcnt orders
//   same-thread RAW). Register-array P is untenable (r5-r9: AGPR hoisting /
//   scratch demotion). Lane l: o-quad q=l&3 (owns o=q*4..+3), rsub=l>>2;
//   wave w covers rows [w*144,(w+1)*144) in 9 passes of 16. W float4 load =
//   16 rows x 64 B fully-consumed lines. fp32 accumulation everywhere; only
//   P storage is bf16 (absmax 0.0078 vs thr 0.0172). Logit state eliminated:
//   logit = dot(accum-out, P) per iter. Unnormalized softmax (fp32-safe).

constexpr int C = 10, B = 128, N = 1152, IN = 8, OUT = 16;
constexpr int THREADS = 512;
constexpr int NW = THREADS / 64;          // 8 waves
constexpr int PASSES = N / (NW * 16);     // 9

__device__ __forceinline__ unsigned packbf(float a, float b) {
    __hip_bfloat162 h = __float22bfloat162_rn(float2{a, b});  // RNE
    return *(unsigned*)&h;
}
__device__ __forceinline__ float bflo(unsigned u) { return __uint_as_float(u << 16); }
__device__ __forceinline__ float bfhi(unsigned u) { return __uint_as_float(u & 0xffff0000u); }

__global__ __launch_bounds__(THREADS)
void caps_route(const float* __restrict__ Xf, const float* __restrict__ Wf,
                float* __restrict__ Of) {
    // P packed: .x = bf16x2(P0,P1), .y = bf16x2(P2,P3); thread-private slots
    __shared__ uint2 ldsP[PASSES * THREADS];   // 36,864 B
    __shared__ float lds_s[NW][OUT];           // per-wave weighted sums
    __shared__ float lds_sum[NW];              // per-wave softmax denoms
    __shared__ float lds_out[OUT];             // squashed output (per iter)

    const int t = threadIdx.x;
    const int l = t & 63;
    const int wid = t >> 6;
    const int q = l & 3;        // o-quad: owns o = q*4 .. q*4+3
    const int rsub = l >> 2;    // row-sub within a pass (0..15)
    const int blk = blockIdx.x;
    const int c = blk >> 7;     // 128 consecutive blocks share c -> W[c] in L2/L3
    const int b = blk & 127;

    // iter-0 fused accumulators (e=1): fp32 sums of this thread's priors
    float s0 = 0.f, s1 = 0.f, s2 = 0.f, s3 = 0.f;

    // ---- priors: P[n][o] = sum_i x[b,n,i] * W[c,n,i,o] (fp32 acc, bf16 store)
    #pragma unroll
    for (int p = 0; p < PASSES; ++p) {
        const int n = wid * (16 * PASSES) + p * 16 + rsub;
        const float4* wr = (const float4*)(Wf + (size_t)(c * N + n) * (IN * OUT));
        float4 wv[IN];
        #pragma unroll
        for (int i = 0; i < IN; ++i) wv[i] = wr[i * 4 + q];   // 16 full lines/instr
        const float4* xr = (const float4*)(Xf + (size_t)(b * N + n) * IN);
        const float4 xa = xr[0], xc = xr[1];
        const float xs[8] = { xa.x, xa.y, xa.z, xa.w, xc.x, xc.y, xc.z, xc.w };
        float a0 = 0.f, a1 = 0.f, a2 = 0.f, a3 = 0.f;
        #pragma unroll
        for (int i = 0; i < IN; ++i) {
            a0 = fmaf(xs[i], wv[i].x, a0);
            a1 = fmaf(xs[i], wv[i].y, a1);
            a2 = fmaf(xs[i], wv[i].z, a2);
            a3 = fmaf(xs[i], wv[i].w, a3);
        }
        ldsP[p * THREADS + t] = uint2{packbf(a0, a1), packbf(a2, a3)};
        s0 += a0; s1 += a1; s2 += a2; s3 += a3;     // iter-0 (e=1) fusion
    }

    // accumulated output quad-slice (fp32); logit[p] == dot(oa_full16, P[p])
    float oa[4] = {0.f, 0.f, 0.f, 0.f};

    // ---- dynamic routing ----
    for (int it = 0; it < 3; ++it) {
        float ssum;
        if (it == 0) {
            ssum = (float)PASSES;       // e = 1 for all logits
            // s0..s3 already hold this thread's prior sums (fused above)
        } else {
            ssum = 0.f;
            s0 = s1 = s2 = s3 = 0.f;
            #pragma unroll
            for (int p = 0; p < PASSES; ++p) {
                const uint2 u = ldsP[p * THREADS + t];
                const float p0 = bflo(u.x), p1 = bfhi(u.x);
                const float p2 = bflo(u.y), p3 = bfhi(u.y);
                // logit = dot(out_accum, P[n,:]) via quad butterfly
                float d = oa[0] * p0;
                d = fmaf(oa[1], p1, d);
                d = fmaf(oa[2], p2, d);
                d = fmaf(oa[3], p3, d);
                d += __shfl_xor(d, 1, 64);
                d += __shfl_xor(d, 2, 64);
                const float e = __expf(d);          // replicated across quad
                ssum += e;
                s0 = fmaf(e, p0, s0);
                s1 = fmaf(e, p1, s1);
                s2 = fmaf(e, p2, s2);
                s3 = fmaf(e, p3, s3);
            }
        }
        // wave reduce across 16 row-subs (masks 4..32; quad bits hold
        // replicas (ssum) / distinct o (s0..s3))
        #pragma unroll
        for (int m = 4; m < 64; m <<= 1) {
            ssum += __shfl_xor(ssum, m, 64);
            s0 += __shfl_xor(s0, m, 64);
            s1 += __shfl_xor(s1, m, 64);
            s2 += __shfl_xor(s2, m, 64);
            s3 += __shfl_xor(s3, m, 64);
        }
        if (l < 4) {                    // lane l == quad q: owns o = l*4..l*4+3
            lds_s[wid][l * 4 + 0] = s0;
            lds_s[wid][l * 4 + 1] = s1;
            lds_s[wid][l * 4 + 2] = s2;
            lds_s[wid][l * 4 + 3] = s3;
        }
        if (l == 0) lds_sum[wid] = ssum;
        __syncthreads();   // A

        // cross-wave combine + squash on t<16
        if (t < OUT) {
            float so = 0.f, S = 0.f;
            #pragma unroll
            for (int w = 0; w < NW; ++w) { so += lds_s[w][t]; S += lds_sum[w]; }
            so /= S;                    // s_o = softmax-weighted prior sum
            float r = so * so;          // ||s||^2 via 16-lane butterfly
            r += __shfl_xor(r, 1, 64);
            r += __shfl_xor(r, 2, 64);
            r += __shfl_xor(r, 4, 64);
            r += __shfl_xor(r, 8, 64);
            const float ov = so * (r / ((1.f + r) * sqrtf(r + 1e-8f)));
            if (it == 2) Of[(size_t)blk * OUT + t] = ov;
            else         lds_out[t] = ov;
        }

        if (it < 2) {
            __syncthreads();   // B
            oa[0] += lds_out[q * 4 + 0];
            oa[1] += lds_out[q * 4 + 1];
            oa[2] += lds_out[q * 4 + 2];
            oa[3] += lds_out[q * 4 + 3];
        }
    }
}

extern "C" void kernel_launch(void* const* d_in, const int* in_sizes, int n_in,
                              void* d_out, int out_size, void* d_ws, size_t ws_size,
                              hipStream_t stream) {
    const float* X = (const float*)d_in[0];   // [B,N,IN] fp32
    const float* W = (const float*)d_in[1];   // [C,N,IN,OUT] fp32
    float* O = (float*)d_out;                 // [C,B,OUT] fp32
    hipLaunchKernelGGL(caps_route, dim3(C * B), dim3(THREADS), 0, stream, X, W, O);
}